// Round 3
// baseline (1145.588 us; speedup 1.0000x reference)
//
#include <hip/hip_runtime.h>

// BilinearAttention B=8, N=2048, H=1024 — MFMA f16-split pipeline, round 3.
//   prep_q : query fp32 -> Qp packed(hi|lo u32)   [staged in d_out attn region]
//   prep_v : value fp32 -> Vp packed [b][n][h] + Vt f16 [b][h][n]
//   prep_w : W fp32 [k][n] -> Wtp packed [n][k]
//   gemm<1>: interP = Qp @ Wtp (3-MFMA split, packed in/out) -> d_out out region
//   gemm<2>: logits = relu(interP @ Vp^T) masked -> d_out attn region (fp32)
//   softmax: rowwise in place + f16 copy (attn16) into ws
//   gemm<3>: out = attn16 @ Vt (plain f16 MFMA) -> d_out out region
//
// ws layout (100 MB): Vt@0 (32M) | Wtp@32M (4M) | Vp@36M (64M)
//   attn16 (67M) aliases @32M..99M  (Wtp dead after gemm1, Vp dead after gemm2)

typedef _Float16 half8 __attribute__((ext_vector_type(8)));
typedef float f32x4 __attribute__((ext_vector_type(4)));
typedef unsigned short u16;
typedef unsigned int u32;

#define BATCH 8
#define SEQ   2048
#define HID   1024
#define MINV  (-1e9f)
#define BK    32
#define RS    40      // LDS row stride in halfs (pad 32 -> 40: 2-way aliasing, free)

__device__ __forceinline__ u16 h2u(_Float16 h) { return __builtin_bit_cast(u16, h); }

__device__ __forceinline__ u32 packhl(float x) {
    _Float16 h = (_Float16)x;
    _Float16 l = (_Float16)(x - (float)h);
    return (u32)h2u(h) | ((u32)h2u(l) << 16);
}

// packed u32x4 -> hi-pair/lo-pair (4 halfs each)
__device__ __forceinline__ void unpack4(const uint4 p, uint2& hv, uint2& lv) {
    hv.x = (p.x & 0xffffu) | (p.y << 16);
    hv.y = (p.z & 0xffffu) | (p.w << 16);
    lv.x = (p.x >> 16) | (p.y & 0xffff0000u);
    lv.y = (p.z >> 16) | (p.w & 0xffff0000u);
}

// ---------------------------------------------------------------------------
// prep_q: elementwise fp32 -> packed hi|lo u32
// ---------------------------------------------------------------------------
__global__ __launch_bounds__(256) void prep_q(const float* __restrict__ q,
                                              u32* __restrict__ qp)
{
    const size_t i = ((size_t)blockIdx.x * 256 + threadIdx.x) * 4;
    const float4 x = *(const float4*)(q + i);
    *(uint4*)(qp + i) = make_uint4(packhl(x.x), packhl(x.y), packhl(x.z), packhl(x.w));
}

// ---------------------------------------------------------------------------
// prep_v: 64x64 tiles. Vp (packed, same layout) coalesced; Vt (f16,
// transposed to [b][h][n]) via LDS transpose.
// ---------------------------------------------------------------------------
__global__ __launch_bounds__(256) void prep_v(const float* __restrict__ V,
                                              u32* __restrict__ Vp,
                                              u16* __restrict__ Vt)
{
    __shared__ __align__(16) u16 lt[64 * 72];
    const int b = blockIdx.z, n0 = blockIdx.y * 64, h0 = blockIdx.x * 64;
    const int t = threadIdx.x;
    const int r = t >> 4, c4 = (t & 15) * 4;
#pragma unroll
    for (int it = 0; it < 4; ++it) {
        const int rr = r + it * 16;
        const float4 x = *(const float4*)(V + ((size_t)b * SEQ + n0 + rr) * HID + h0 + c4);
        const float xs[4] = {x.x, x.y, x.z, x.w};
        u32 p[4];
#pragma unroll
        for (int e = 0; e < 4; ++e) {
            _Float16 h = (_Float16)xs[e];
            _Float16 l = (_Float16)(xs[e] - (float)h);
            p[e] = (u32)h2u(h) | ((u32)h2u(l) << 16);
            lt[(c4 + e) * 72 + rr] = h2u(h);
        }
        *(uint4*)(Vp + ((size_t)b * SEQ + n0 + rr) * HID + h0 + c4) =
            make_uint4(p[0], p[1], p[2], p[3]);
    }
    __syncthreads();
    const int hr = t >> 2, cc = (t & 3) * 2;
    uint4 v0 = *(const uint4*)&lt[hr * 72 + cc * 8];
    uint4 v1 = *(const uint4*)&lt[hr * 72 + cc * 8 + 8];
    u16* dst = Vt + ((size_t)b * HID + h0 + hr) * SEQ + n0 + cc * 8;
    *(uint4*)dst = v0;
    *(uint4*)(dst + 8) = v1;
}

// ---------------------------------------------------------------------------
// prep_w: W [k][n] fp32 -> Wtp [n][k] packed hi/lo u32, 64x64 LDS transpose.
// ---------------------------------------------------------------------------
__global__ __launch_bounds__(256) void prep_w(const float* __restrict__ W,
                                              u32* __restrict__ Wtp)
{
    __shared__ __align__(16) u32 lt[64 * 68];
    const int n0 = blockIdx.x * 64, k0 = blockIdx.y * 64;
    const int t = threadIdx.x;
    const int r = t >> 4, c4 = (t & 15) * 4;
#pragma unroll
    for (int it = 0; it < 4; ++it) {
        const int rr = r + it * 16;
        const float4 x = *(const float4*)(W + (size_t)(k0 + rr) * HID + n0 + c4);
        const float xs[4] = {x.x, x.y, x.z, x.w};
#pragma unroll
        for (int e = 0; e < 4; ++e) lt[(c4 + e) * 68 + rr] = packhl(xs[e]);
    }
    __syncthreads();
    const int n = t >> 2;
#pragma unroll
    for (int s = 0; s < 4; ++s) {
        const int ci = (t & 3) + s * 4;
        uint4 v = *(const uint4*)&lt[n * 68 + ci * 4];
        *(uint4*)(Wtp + (size_t)(n0 + n) * HID + k0 + ci * 4) = v;
    }
}

// ---------------------------------------------------------------------------
// MFMA GEMM, 128x128 block tile, BK=32, 4 waves (each 64x64 = 4x4 MFMA tiles).
// MODE 1: A packed, B packed, 3-MFMA split, C packed-u32           [gemm1]
// MODE 2: A packed, B packed, 3-MFMA split, relu+mask, C fp32      [gemm2]
// MODE 3: A f16, B f16, single MFMA, C fp32                        [gemm3]
// LDS: [row][k] halfs, stride RS=40.
// 16x16x32_f16 fragments: A/B: row/col=lane&15, k=(lane>>4)*8+j.
// C/D: col=lane&15, row=(lane>>4)*4+reg.
// ---------------------------------------------------------------------------
template <int MODE>
__global__ __launch_bounds__(256) void gemm_mfma(
    const void* __restrict__ Abase, const void* __restrict__ Bbase,
    void* __restrict__ Cbase, const int* __restrict__ Mbase,
    int M, int N, int K, int lda, int ldb, int ldc,
    long sA, long sB, long sC, long sM)
{
    constexpr bool SPLIT = (MODE != 3);
    const int b = blockIdx.z;
    const int tid = threadIdx.x;
    const int m0 = blockIdx.y * 128, n0 = blockIdx.x * 128;

    __shared__ __align__(16) u16 smem[(SPLIT ? 4 : 2) * 128 * RS];
    u16* Ah = smem;
    u16* Al = smem + 128 * RS;
    u16* Bh = smem + (SPLIT ? 2 : 1) * 128 * RS;
    u16* Bl = smem + 3 * 128 * RS;

    const int srow = tid >> 1;            // staging row 0..127
    const int skb = (tid & 1) * 16;       // staging k base 0/16

    const int w = tid >> 6, lane = tid & 63;
    const int wr = (w >> 1) * 64, wc = (w & 1) * 64;
    const int lm = lane & 15, q = lane >> 4;

    f32x4 acc[4][4];
#pragma unroll
    for (int i = 0; i < 4; ++i)
#pragma unroll
        for (int j = 0; j < 4; ++j) acc[i][j] = (f32x4){0.f, 0.f, 0.f, 0.f};

    for (int k0 = 0; k0 < K; k0 += BK) {
        uint2 AH[4], AL[4], BH[4], BL[4];
        uint4 acopy[2], bcopy[2];
        // ---- global loads (+unpack for split modes) ----
        if constexpr (SPLIT) {
            const u32* Ap = (const u32*)Abase + (long)b * sA + (long)(m0 + srow) * lda + k0 + skb;
            const u32* Bp = (const u32*)Bbase + (long)b * sB + (long)(n0 + srow) * ldb + k0 + skb;
#pragma unroll
            for (int c = 0; c < 4; ++c) unpack4(*(const uint4*)(Ap + 4 * c), AH[c], AL[c]);
#pragma unroll
            for (int c = 0; c < 4; ++c) unpack4(*(const uint4*)(Bp + 4 * c), BH[c], BL[c]);
        } else {
            const u16* Af = (const u16*)Abase + (long)b * sA + (long)(m0 + srow) * lda + k0 + skb;
            const u16* Bf = (const u16*)Bbase + (long)b * sB + (long)(n0 + srow) * ldb + k0 + skb;
            acopy[0] = ((const uint4*)Af)[0];
            acopy[1] = ((const uint4*)Af)[1];
            bcopy[0] = ((const uint4*)Bf)[0];
            bcopy[1] = ((const uint4*)Bf)[1];
        }
        __syncthreads();
        // ---- LDS stores ----
        if constexpr (SPLIT) {
#pragma unroll
            for (int c = 0; c < 4; ++c) {
                *(uint2*)&Ah[srow * RS + skb + 4 * c] = AH[c];
                *(uint2*)&Al[srow * RS + skb + 4 * c] = AL[c];
                *(uint2*)&Bh[srow * RS + skb + 4 * c] = BH[c];
                *(uint2*)&Bl[srow * RS + skb + 4 * c] = BL[c];
            }
        } else {
            *(uint4*)&Ah[srow * RS + skb] = acopy[0];
            *(uint4*)&Ah[srow * RS + skb + 8] = acopy[1];
            *(uint4*)&Bh[srow * RS + skb] = bcopy[0];
            *(uint4*)&Bh[srow * RS + skb + 8] = bcopy[1];
        }
        __syncthreads();
        // ---- MFMA ----
        half8 af[4], alf[4];
#pragma unroll
        for (int i = 0; i < 4; ++i) {
            const int ro = (wr + i * 16 + lm) * RS + q * 8;
            af[i] = *(const half8*)&Ah[ro];
            if constexpr (SPLIT) alf[i] = *(const half8*)&Al[ro];
        }
#pragma unroll
        for (int j = 0; j < 4; ++j) {
            const int co = (wc + j * 16 + lm) * RS + q * 8;
            half8 bf = *(const half8*)&Bh[co];
            half8 blf;
            if constexpr (SPLIT) blf = *(const half8*)&Bl[co];
#pragma unroll
            for (int i = 0; i < 4; ++i) {
                if constexpr (SPLIT) {
                    acc[i][j] = __builtin_amdgcn_mfma_f32_16x16x32_f16(alf[i], bf, acc[i][j], 0, 0, 0);
                    acc[i][j] = __builtin_amdgcn_mfma_f32_16x16x32_f16(af[i], blf, acc[i][j], 0, 0, 0);
                }
                acc[i][j] = __builtin_amdgcn_mfma_f32_16x16x32_f16(af[i], bf, acc[i][j], 0, 0, 0);
            }
        }
    }

    // ---- epilogue ----
#pragma unroll
    for (int i = 0; i < 4; ++i) {
#pragma unroll
        for (int r = 0; r < 4; ++r) {
            const int grow = m0 + wr + i * 16 + q * 4 + r;
#pragma unroll
            for (int j = 0; j < 4; ++j) {
                const int gcol = n0 + wc + j * 16 + lm;
                const float v = acc[i][j][r];
                if constexpr (MODE == 1) {
                    ((u32*)Cbase)[(long)grow * ldc + gcol] = packhl(v);
                } else if constexpr (MODE == 2) {
                    const int mv = Mbase[(long)b * sM + (long)grow * ldc + gcol];
                    ((float*)Cbase)[(long)b * sC + (long)grow * ldc + gcol] =
                        (mv > 0) ? fmaxf(v, 0.f) : MINV;
                } else {
                    ((float*)Cbase)[(long)b * sC + (long)grow * ldc + gcol] = v;
                }
            }
        }
    }
}

// ---------------------------------------------------------------------------
// Row softmax over 2048 elements, in place (fp32) + f16 copy to p16.
// ---------------------------------------------------------------------------
__global__ __launch_bounds__(256) void softmax2048(float* __restrict__ attn,
                                                   u16* __restrict__ attn16)
{
    const long row = blockIdx.x;
    float* p = attn + row * 2048;
    u16* p16 = attn16 + row * 2048;
    const int tid = threadIdx.x;

    float4 v0 = ((const float4*)p)[tid];
    float4 v1 = ((const float4*)p)[tid + 256];

    float mx = fmaxf(fmaxf(fmaxf(v0.x, v0.y), fmaxf(v0.z, v0.w)),
                     fmaxf(fmaxf(v1.x, v1.y), fmaxf(v1.z, v1.w)));
#pragma unroll
    for (int o = 32; o >= 1; o >>= 1)
        mx = fmaxf(mx, __shfl_xor(mx, o, 64));

    __shared__ float redm[4];
    __shared__ float reds[4];
    const int wid = tid >> 6, lane = tid & 63;
    if (lane == 0) redm[wid] = mx;
    __syncthreads();
    mx = fmaxf(fmaxf(redm[0], redm[1]), fmaxf(redm[2], redm[3]));

    float e[8];
    e[0] = __expf(v0.x - mx); e[1] = __expf(v0.y - mx);
    e[2] = __expf(v0.z - mx); e[3] = __expf(v0.w - mx);
    e[4] = __expf(v1.x - mx); e[5] = __expf(v1.y - mx);
    e[6] = __expf(v1.z - mx); e[7] = __expf(v1.w - mx);

    float s = ((e[0] + e[1]) + (e[2] + e[3])) + ((e[4] + e[5]) + (e[6] + e[7]));
#pragma unroll
    for (int o = 32; o >= 1; o >>= 1)
        s += __shfl_xor(s, o, 64);
    if (lane == 0) reds[wid] = s;
    __syncthreads();
    s = (reds[0] + reds[1]) + (reds[2] + reds[3]);

    const float inv = 1.0f / s;
    float a[8];
#pragma unroll
    for (int k = 0; k < 8; ++k) a[k] = e[k] * inv;
    ((float4*)p)[tid]       = make_float4(a[0], a[1], a[2], a[3]);
    ((float4*)p)[tid + 256] = make_float4(a[4], a[5], a[6], a[7]);

    uint2 h0, h1;
    h0.x = (u32)h2u((_Float16)a[0]) | ((u32)h2u((_Float16)a[1]) << 16);
    h0.y = (u32)h2u((_Float16)a[2]) | ((u32)h2u((_Float16)a[3]) << 16);
    h1.x = (u32)h2u((_Float16)a[4]) | ((u32)h2u((_Float16)a[5]) << 16);
    h1.y = (u32)h2u((_Float16)a[6]) | ((u32)h2u((_Float16)a[7]) << 16);
    ((uint2*)p16)[tid]       = h0;
    ((uint2*)p16)[tid + 256] = h1;
}

extern "C" void kernel_launch(void* const* d_in, const int* in_sizes, int n_in,
                              void* d_out, int out_size, void* d_ws, size_t ws_size,
                              hipStream_t stream)
{
    (void)in_sizes; (void)n_in; (void)out_size; (void)ws_size;

    const float* query = (const float*)d_in[0];  // B,N,H
    const float* value = (const float*)d_in[1];  // B,N,H
    const int*   mask  = (const int*)d_in[2];    // B,N,N
    const float* W     = (const float*)d_in[3];  // H,H

    float* out  = (float*)d_out;                           // B*N*H
    float* attn = out + (size_t)BATCH * SEQ * HID;         // B*N*N

    // ws: Vt@0 (32M) | Wtp@32M (4M) | Vp@36M (64M); attn16 aliases @32M (67M)
    u16* Vt     = (u16*)d_ws;
    u32* Wtp    = (u32*)((char*)d_ws + ((size_t)32 << 20));
    u32* Vp     = (u32*)((char*)d_ws + ((size_t)36 << 20));
    u16* attn16 = (u16*)((char*)d_ws + ((size_t)32 << 20));

    // Qp staged in d_out attn region (dead until gemm2 writes attn);
    // interP staged in d_out output region (dead after gemm2 reads it).
    u32* Qp     = (u32*)attn;
    u32* interP = (u32*)d_out;

    prep_q<<<dim3((BATCH * SEQ * HID) / 1024), 256, 0, stream>>>(query, Qp);
    prep_v<<<dim3(HID / 64, SEQ / 64, BATCH), 256, 0, stream>>>(value, Vp, Vt);
    prep_w<<<dim3(HID / 64, HID / 64, 1), 256, 0, stream>>>(W, Wtp);

    // gemm1: interP[BN,1024] = Qp @ Wtp  (packed in/out)
    gemm_mfma<1><<<dim3(HID / 128, (BATCH * SEQ) / 128, 1), 256, 0, stream>>>(
        Qp, Wtp, interP, nullptr,
        BATCH * SEQ, HID, HID, HID, HID, HID, 0, 0, 0, 0);

    // gemm2: logits = relu(interP @ Vp^T) masked -> attn region (fp32)
    gemm_mfma<2><<<dim3(SEQ / 128, SEQ / 128, BATCH), 256, 0, stream>>>(
        interP, Vp, attn, mask,
        SEQ, SEQ, HID, HID, HID, SEQ,
        (long)SEQ * HID, (long)SEQ * HID, (long)SEQ * SEQ, (long)SEQ * SEQ);

    softmax2048<<<dim3(BATCH * SEQ), 256, 0, stream>>>(attn, attn16);

    // gemm3: out = attn16 @ Vt  (plain f16)
    gemm_mfma<3><<<dim3(HID / 128, SEQ / 128, BATCH), 256, 0, stream>>>(
        attn16, Vt, out, nullptr,
        SEQ, HID, SEQ, SEQ, SEQ, HID,
        (long)SEQ * SEQ, (long)HID * SEQ, (long)SEQ * HID, 0);
}

// Round 4
// 1097.259 us; speedup vs baseline: 1.0440x; 1.0440x over previous
//
#include <hip/hip_runtime.h>

// BilinearAttention B=8, N=2048, H=1024 — MFMA f16-split pipeline, round 4.
//   prep_q : query fp32 -> Qp packed(hi|lo u32)   [staged in d_out attn region]
//   prep_v : value fp32 -> Vp packed [b][n][h] + Vt f16 [b][h][n]
//   prep_w : W fp32 [k][n] -> Wtp packed [n][k]
//   gemm<1>: interP = Qp @ Wtp (3-MFMA split) -> d_out out region (packed u32)
//   gemm<2>: logits = relu(interP @ Vp^T) masked -> d_out attn region (fp32)
//   softmax: rowwise in place + f16 copy (attn16) into ws
//   gemm<3>: out = attn16 @ Vt (plain f16 MFMA) -> d_out out region
//
// Round-4: (a) epilogue LDS-transpose -> float4/uint4 coalesced C stores
// (fixes 12x TCC write amplification seen with per-lane dword scatter);
// (b) XCD-aware block swizzle (id&7 = XCD heuristic) so A/B panels stay in
// one XCD's L2 instead of being replicated into all 8.
//
// ws layout (100 MB): Vt@0 (32M) | Wtp@32M (4M) | Vp@36M (64M)
//   attn16 (67M) aliases @32M..99M  (Wtp dead after gemm1, Vp dead after gemm2)

typedef _Float16 half8 __attribute__((ext_vector_type(8)));
typedef float f32x4 __attribute__((ext_vector_type(4)));
typedef unsigned short u16;
typedef unsigned int u32;

#define BATCH 8
#define SEQ   2048
#define HID   1024
#define MINV  (-1e9f)
#define BK    32
#define RS    40      // LDS row stride in halfs (pad 32 -> 40: 2-way aliasing, free)
#define EPS   66      // epilogue slab row stride in floats

__device__ __forceinline__ u16 h2u(_Float16 h) { return __builtin_bit_cast(u16, h); }

__device__ __forceinline__ u32 packhl(float x) {
    _Float16 h = (_Float16)x;
    _Float16 l = (_Float16)(x - (float)h);
    return (u32)h2u(h) | ((u32)h2u(l) << 16);
}

// packed u32x4 -> hi-pair/lo-pair (4 halfs each)
__device__ __forceinline__ void unpack4(const uint4 p, uint2& hv, uint2& lv) {
    hv.x = (p.x & 0xffffu) | (p.y << 16);
    hv.y = (p.z & 0xffffu) | (p.w << 16);
    lv.x = (p.x >> 16) | (p.y & 0xffff0000u);
    lv.y = (p.z >> 16) | (p.w & 0xffff0000u);
}

// ---------------------------------------------------------------------------
__global__ __launch_bounds__(256) void prep_q(const float* __restrict__ q,
                                              u32* __restrict__ qp)
{
    const size_t i = ((size_t)blockIdx.x * 256 + threadIdx.x) * 4;
    const float4 x = *(const float4*)(q + i);
    *(uint4*)(qp + i) = make_uint4(packhl(x.x), packhl(x.y), packhl(x.z), packhl(x.w));
}

// ---------------------------------------------------------------------------
__global__ __launch_bounds__(256) void prep_v(const float* __restrict__ V,
                                              u32* __restrict__ Vp,
                                              u16* __restrict__ Vt)
{
    __shared__ __align__(16) u16 lt[64 * 72];
    const int b = blockIdx.z, n0 = blockIdx.y * 64, h0 = blockIdx.x * 64;
    const int t = threadIdx.x;
    const int r = t >> 4, c4 = (t & 15) * 4;
#pragma unroll
    for (int it = 0; it < 4; ++it) {
        const int rr = r + it * 16;
        const float4 x = *(const float4*)(V + ((size_t)b * SEQ + n0 + rr) * HID + h0 + c4);
        const float xs[4] = {x.x, x.y, x.z, x.w};
        u32 p[4];
#pragma unroll
        for (int e = 0; e < 4; ++e) {
            _Float16 h = (_Float16)xs[e];
            _Float16 l = (_Float16)(xs[e] - (float)h);
            p[e] = (u32)h2u(h) | ((u32)h2u(l) << 16);
            lt[(c4 + e) * 72 + rr] = h2u(h);
        }
        *(uint4*)(Vp + ((size_t)b * SEQ + n0 + rr) * HID + h0 + c4) =
            make_uint4(p[0], p[1], p[2], p[3]);
    }
    __syncthreads();
    const int hr = t >> 2, cc = (t & 3) * 2;
    uint4 v0 = *(const uint4*)&lt[hr * 72 + cc * 8];
    uint4 v1 = *(const uint4*)&lt[hr * 72 + cc * 8 + 8];
    u16* dst = Vt + ((size_t)b * HID + h0 + hr) * SEQ + n0 + cc * 8;
    *(uint4*)dst = v0;
    *(uint4*)(dst + 8) = v1;
}

// ---------------------------------------------------------------------------
__global__ __launch_bounds__(256) void prep_w(const float* __restrict__ W,
                                              u32* __restrict__ Wtp)
{
    __shared__ __align__(16) u32 lt[64 * 68];
    const int n0 = blockIdx.x * 64, k0 = blockIdx.y * 64;
    const int t = threadIdx.x;
    const int r = t >> 4, c4 = (t & 15) * 4;
#pragma unroll
    for (int it = 0; it < 4; ++it) {
        const int rr = r + it * 16;
        const float4 x = *(const float4*)(W + (size_t)(k0 + rr) * HID + n0 + c4);
        const float xs[4] = {x.x, x.y, x.z, x.w};
#pragma unroll
        for (int e = 0; e < 4; ++e) lt[(c4 + e) * 68 + rr] = packhl(xs[e]);
    }
    __syncthreads();
    const int n = t >> 2;
#pragma unroll
    for (int s = 0; s < 4; ++s) {
        const int ci = (t & 3) + s * 4;
        uint4 v = *(const uint4*)&lt[n * 68 + ci * 4];
        *(uint4*)(Wtp + (size_t)(n0 + n) * HID + k0 + ci * 4) = v;
    }
}

// ---------------------------------------------------------------------------
// MFMA GEMM, 128x128 block tile, BK=32, 4 waves (each 64x64 = 4x4 MFMA tiles).
// MODE 1: A packed, B packed, 3-MFMA split, C packed-u32           [gemm1]
// MODE 2: A packed, B packed, 3-MFMA split, relu+mask, C fp32      [gemm2]
// MODE 3: A f16, B f16, single MFMA, C fp32                        [gemm3]
// XBLOG > 0: 1-D grid, XCD swizzle: xcd = id&7 owns 16 (b,y) panels.
//   MODE 1: panels are M-chunks (b=0). MODE 2/3: b = xcd, 16 y-panels.
// Epilogue: per-wave 64x64 quadrant -> LDS slab (16x66 f32) -> float4 stores.
// ---------------------------------------------------------------------------
template <int MODE, int XBLOG>
__global__ __launch_bounds__(256) void gemm_mfma(
    const void* __restrict__ Abase, const void* __restrict__ Bbase,
    void* __restrict__ Cbase, const int* __restrict__ Mbase,
    int M, int N, int K, int lda, int ldb, int ldc,
    long sA, long sB, long sC, long sM)
{
    constexpr bool SPLIT = (MODE != 3);
    const int tid = threadIdx.x;

    int b, m0, n0;
    if constexpr (XBLOG > 0) {
        const int id = blockIdx.x;
        const int xcd = id & 7;
        const int j = id >> 3;
        const int pidx = xcd * 16 + (j >> XBLOG);     // 0..127
        n0 = (j & ((1 << XBLOG) - 1)) * 128;
        if constexpr (MODE == 1) { b = 0; m0 = pidx * 128; }
        else { b = pidx >> 4; m0 = (pidx & 15) * 128; }
    } else {
        b = blockIdx.z; m0 = blockIdx.y * 128; n0 = blockIdx.x * 128;
    }

    __shared__ __align__(16) u16 smem[(SPLIT ? 4 : 2) * 128 * RS];
    u16* Ah = smem;
    u16* Al = smem + 128 * RS;
    u16* Bh = smem + (SPLIT ? 2 : 1) * 128 * RS;
    u16* Bl = smem + 3 * 128 * RS;

    const int srow = tid >> 1;            // staging row 0..127
    const int skb = (tid & 1) * 16;       // staging k base 0/16

    const int w = tid >> 6, lane = tid & 63;
    const int wr = (w >> 1) * 64, wc = (w & 1) * 64;
    const int lm = lane & 15, q = lane >> 4;

    f32x4 acc[4][4];
#pragma unroll
    for (int i = 0; i < 4; ++i)
#pragma unroll
        for (int j = 0; j < 4; ++j) acc[i][j] = (f32x4){0.f, 0.f, 0.f, 0.f};

    for (int k0 = 0; k0 < K; k0 += BK) {
        uint2 AH[4], AL[4], BH[4], BL[4];
        uint4 acopy[2], bcopy[2];
        if constexpr (SPLIT) {
            const u32* Ap = (const u32*)Abase + (long)b * sA + (long)(m0 + srow) * lda + k0 + skb;
            const u32* Bp = (const u32*)Bbase + (long)b * sB + (long)(n0 + srow) * ldb + k0 + skb;
#pragma unroll
            for (int c = 0; c < 4; ++c) unpack4(*(const uint4*)(Ap + 4 * c), AH[c], AL[c]);
#pragma unroll
            for (int c = 0; c < 4; ++c) unpack4(*(const uint4*)(Bp + 4 * c), BH[c], BL[c]);
        } else {
            const u16* Af = (const u16*)Abase + (long)b * sA + (long)(m0 + srow) * lda + k0 + skb;
            const u16* Bf = (const u16*)Bbase + (long)b * sB + (long)(n0 + srow) * ldb + k0 + skb;
            acopy[0] = ((const uint4*)Af)[0];
            acopy[1] = ((const uint4*)Af)[1];
            bcopy[0] = ((const uint4*)Bf)[0];
            bcopy[1] = ((const uint4*)Bf)[1];
        }
        __syncthreads();
        if constexpr (SPLIT) {
#pragma unroll
            for (int c = 0; c < 4; ++c) {
                *(uint2*)&Ah[srow * RS + skb + 4 * c] = AH[c];
                *(uint2*)&Al[srow * RS + skb + 4 * c] = AL[c];
                *(uint2*)&Bh[srow * RS + skb + 4 * c] = BH[c];
                *(uint2*)&Bl[srow * RS + skb + 4 * c] = BL[c];
            }
        } else {
            *(uint4*)&Ah[srow * RS + skb] = acopy[0];
            *(uint4*)&Ah[srow * RS + skb + 8] = acopy[1];
            *(uint4*)&Bh[srow * RS + skb] = bcopy[0];
            *(uint4*)&Bh[srow * RS + skb + 8] = bcopy[1];
        }
        __syncthreads();
        half8 af[4], alf[4];
#pragma unroll
        for (int i = 0; i < 4; ++i) {
            const int ro = (wr + i * 16 + lm) * RS + q * 8;
            af[i] = *(const half8*)&Ah[ro];
            if constexpr (SPLIT) alf[i] = *(const half8*)&Al[ro];
        }
#pragma unroll
        for (int j = 0; j < 4; ++j) {
            const int co = (wc + j * 16 + lm) * RS + q * 8;
            half8 bf = *(const half8*)&Bh[co];
            half8 blf;
            if constexpr (SPLIT) blf = *(const half8*)&Bl[co];
#pragma unroll
            for (int i = 0; i < 4; ++i) {
                if constexpr (SPLIT) {
                    acc[i][j] = __builtin_amdgcn_mfma_f32_16x16x32_f16(alf[i], bf, acc[i][j], 0, 0, 0);
                    acc[i][j] = __builtin_amdgcn_mfma_f32_16x16x32_f16(af[i], blf, acc[i][j], 0, 0, 0);
                }
                acc[i][j] = __builtin_amdgcn_mfma_f32_16x16x32_f16(af[i], bf, acc[i][j], 0, 0, 0);
            }
        }
    }

    // ---- epilogue: transpose each wave's 64x64 quadrant through LDS ----
    __syncthreads();                       // all waves done reading smem
    float* ep = (float*)smem + w * (16 * EPS);   // per-wave slab 16x66 f32
    const int lrq = lane >> 4;             // 0..3 (row group for readback)
    const int cc = lane & 15;              // col group (x4 floats)
    const int* Mk = (MODE == 2) ? (Mbase + (long)b * sM) : nullptr;

#pragma unroll
    for (int i = 0; i < 4; ++i) {
        // write phase: scatter acc[i] into slab (2-way bank aliasing, free)
#pragma unroll
        for (int j = 0; j < 4; ++j)
#pragma unroll
            for (int r = 0; r < 4; ++r)
                ep[(q * 4 + r) * EPS + j * 16 + lm] = acc[i][j][r];
        __syncthreads();
        // read phase: row-major float4 -> coalesced global stores
#pragma unroll
        for (int p = 0; p < 4; ++p) {
            const int r2 = p * 4 + lrq;
            const float4 v = *(const float4*)&ep[r2 * EPS + cc * 4];
            const long grow = m0 + wr + i * 16 + r2;
            const long gcol = n0 + wc + cc * 4;
            if constexpr (MODE == 1) {
                *(uint4*)((u32*)Cbase + grow * ldc + gcol) =
                    make_uint4(packhl(v.x), packhl(v.y), packhl(v.z), packhl(v.w));
            } else if constexpr (MODE == 2) {
                const int4 mv = *(const int4*)(Mk + grow * ldc + gcol);
                float o[4] = {v.x, v.y, v.z, v.w};
                const int mi[4] = {mv.x, mv.y, mv.z, mv.w};
#pragma unroll
                for (int e = 0; e < 4; ++e)
                    o[e] = (mi[e] > 0) ? fmaxf(o[e], 0.f) : MINV;
                *(float4*)((float*)Cbase + (long)b * sC + grow * ldc + gcol) =
                    make_float4(o[0], o[1], o[2], o[3]);
            } else {
                *(float4*)((float*)Cbase + (long)b * sC + grow * ldc + gcol) = v;
            }
        }
        __syncthreads();
    }
}

// ---------------------------------------------------------------------------
__global__ __launch_bounds__(256) void softmax2048(float* __restrict__ attn,
                                                   u16* __restrict__ attn16)
{
    const long row = blockIdx.x;
    float* p = attn + row * 2048;
    u16* p16 = attn16 + row * 2048;
    const int tid = threadIdx.x;

    float4 v0 = ((const float4*)p)[tid];
    float4 v1 = ((const float4*)p)[tid + 256];

    float mx = fmaxf(fmaxf(fmaxf(v0.x, v0.y), fmaxf(v0.z, v0.w)),
                     fmaxf(fmaxf(v1.x, v1.y), fmaxf(v1.z, v1.w)));
#pragma unroll
    for (int o = 32; o >= 1; o >>= 1)
        mx = fmaxf(mx, __shfl_xor(mx, o, 64));

    __shared__ float redm[4];
    __shared__ float reds[4];
    const int wid = tid >> 6, lane = tid & 63;
    if (lane == 0) redm[wid] = mx;
    __syncthreads();
    mx = fmaxf(fmaxf(redm[0], redm[1]), fmaxf(redm[2], redm[3]));

    float e[8];
    e[0] = __expf(v0.x - mx); e[1] = __expf(v0.y - mx);
    e[2] = __expf(v0.z - mx); e[3] = __expf(v0.w - mx);
    e[4] = __expf(v1.x - mx); e[5] = __expf(v1.y - mx);
    e[6] = __expf(v1.z - mx); e[7] = __expf(v1.w - mx);

    float s = ((e[0] + e[1]) + (e[2] + e[3])) + ((e[4] + e[5]) + (e[6] + e[7]));
#pragma unroll
    for (int o = 32; o >= 1; o >>= 1)
        s += __shfl_xor(s, o, 64);
    if (lane == 0) reds[wid] = s;
    __syncthreads();
    s = (reds[0] + reds[1]) + (reds[2] + reds[3]);

    const float inv = 1.0f / s;
    float a[8];
#pragma unroll
    for (int k = 0; k < 8; ++k) a[k] = e[k] * inv;
    ((float4*)p)[tid]       = make_float4(a[0], a[1], a[2], a[3]);
    ((float4*)p)[tid + 256] = make_float4(a[4], a[5], a[6], a[7]);

    uint2 h0, h1;
    h0.x = (u32)h2u((_Float16)a[0]) | ((u32)h2u((_Float16)a[1]) << 16);
    h0.y = (u32)h2u((_Float16)a[2]) | ((u32)h2u((_Float16)a[3]) << 16);
    h1.x = (u32)h2u((_Float16)a[4]) | ((u32)h2u((_Float16)a[5]) << 16);
    h1.y = (u32)h2u((_Float16)a[6]) | ((u32)h2u((_Float16)a[7]) << 16);
    ((uint2*)p16)[tid]       = h0;
    ((uint2*)p16)[tid + 256] = h1;
}

extern "C" void kernel_launch(void* const* d_in, const int* in_sizes, int n_in,
                              void* d_out, int out_size, void* d_ws, size_t ws_size,
                              hipStream_t stream)
{
    (void)in_sizes; (void)n_in; (void)out_size; (void)ws_size;

    const float* query = (const float*)d_in[0];  // B,N,H
    const float* value = (const float*)d_in[1];  // B,N,H
    const int*   mask  = (const int*)d_in[2];    // B,N,N
    const float* W     = (const float*)d_in[3];  // H,H

    float* out  = (float*)d_out;                           // B*N*H
    float* attn = out + (size_t)BATCH * SEQ * HID;         // B*N*N

    // ws: Vt@0 (32M) | Wtp@32M (4M) | Vp@36M (64M); attn16 aliases @32M (67M)
    u16* Vt     = (u16*)d_ws;
    u32* Wtp    = (u32*)((char*)d_ws + ((size_t)32 << 20));
    u32* Vp     = (u32*)((char*)d_ws + ((size_t)36 << 20));
    u16* attn16 = (u16*)((char*)d_ws + ((size_t)32 << 20));

    // Qp staged in d_out attn region (dead until gemm2 writes attn);
    // interP staged in d_out output region (dead after gemm2 reads it).
    u32* Qp     = (u32*)attn;
    u32* interP = (u32*)d_out;

    prep_q<<<dim3((BATCH * SEQ * HID) / 1024), 256, 0, stream>>>(query, Qp);
    prep_v<<<dim3(HID / 64, SEQ / 64, BATCH), 256, 0, stream>>>(value, Vp, Vt);
    prep_w<<<dim3(HID / 64, HID / 64, 1), 256, 0, stream>>>(W, Wtp);

    // gemm1: interP[BN,1024] = Qp @ Wtp   (XCD swizzle: 8 x-blocks/panel)
    gemm_mfma<1, 3><<<dim3(1024, 1, 1), 256, 0, stream>>>(
        Qp, Wtp, interP, nullptr,
        BATCH * SEQ, HID, HID, HID, HID, HID, 0, 0, 0, 0);

    // gemm2: logits = relu(interP @ Vp^T) masked   (16 x-blocks/panel, b=xcd)
    gemm_mfma<2, 4><<<dim3(2048, 1, 1), 256, 0, stream>>>(
        interP, Vp, attn, mask,
        SEQ, SEQ, HID, HID, HID, SEQ,
        (long)SEQ * HID, (long)SEQ * HID, (long)SEQ * SEQ, (long)SEQ * SEQ);

    softmax2048<<<dim3(BATCH * SEQ), 256, 0, stream>>>(attn, attn16);

    // gemm3: out = attn16 @ Vt   (8 x-blocks/panel, b=xcd)
    gemm_mfma<3, 3><<<dim3(1024, 1, 1), 256, 0, stream>>>(
        attn16, Vt, out, nullptr,
        SEQ, HID, SEQ, SEQ, SEQ, HID,
        (long)SEQ * SEQ, (long)HID * SEQ, (long)SEQ * HID, 0);
}